// Round 4
// baseline (247.214 us; speedup 1.0000x reference)
//
#include <hip/hip_runtime.h>
#include <hip/hip_fp16.h>

// CTC-like forward scan. R15 = R14 + REAL register prefetch + coalesced layout.
//   G_t[p] = G_{t-1}[p] + W_t[p] * G_{t-1}[p-1],  W = exp(x_i - x_4)
// R14 evidence: VGPR_Count=52 proves the C-level "register windows" (needs 64
// VGPRs) were demoted -- compiler remat'd them as at-use ds_read_b128, exposing
// ~120cy LDS latency every 8-step window (the ~60% stall implied by VALUBusy).
// Fix: inline-asm ds_read_b128 bursts into 3 rotating register windows,
// issued TWO windows ahead (burst latency ~170cy > window ~110cy), waited
// with lgkmcnt(8) (leaves the 1-ahead burst in flight). sched_barrier(0)
// after waitcnt (rule: compiler hoists reg-only ops past asm waitcnt);
// keep-alive asm after final drain (async ds_read dests must stay allocated).
// Layout: xq[b][t] (column-major) -> scan staging gloads are coalesced 1KB/
// wave (was 16B/lane at 1KB stride = 4x line re-fetch across blocks; measured
// FETCH 16.5MB vs 4.2MB ideal). Prepass writes coalesced, reads strided (L2
// absorbs). Numerics identical to R14 (absmax 0.0): f16 weights via v_perm +
// v_fma_mix_f32, renorm every 8 steps, down-only alignment, boundary via one
// v_mov_dpp wave_shr:1, logs = sum x4 in f32.

#define TT 4096
#define BB 64
#define PP 512
#define LN2F 0.69314718055994531f

typedef unsigned u32x4 __attribute__((ext_vector_type(4)));

__device__ __forceinline__ unsigned f16_bits(float f) {
    return (unsigned)__half_as_ushort(__float2half(f));   // v_cvt_f16_f32, RNE
}

// prepass: x[t][b][5] -> xq[b*4096+t] = {f16W0|W1, f16W2|W3, f32 x4, 0}
// j = b*4096 + t: writes coalesced; reads strided 320B (L2-cached, 5MB input).
__global__ __launch_bounds__(256, 1)
void ctc_prepass(const float* __restrict__ x, u32x4* __restrict__ xq) {
    int j = blockIdx.x * 256 + threadIdx.x;
    int b = j >> 12, t = j & 4095;
    const float* r = x + (size_t)(t * 64 + b) * 5;
    float x0 = r[0], x1 = r[1], x2 = r[2], x3 = r[3], x4 = r[4];
    float w0 = fminf(__expf(x0 - x4), 65000.0f);   // clamp: f16 inf insurance
    float w1 = fminf(__expf(x1 - x4), 65000.0f);
    float w2 = fminf(__expf(x2 - x4), 65000.0f);
    float w3 = fminf(__expf(x3 - x4), 65000.0f);
    u32x4 o;
    o[0] = f16_bits(w0) | (f16_bits(w1) << 16);
    o[1] = f16_bits(w2) | (f16_bits(w3) << 16);
    o[2] = __float_as_uint(x4);
    o[3] = 0u;
    xq[j] = o;
}

__device__ __forceinline__ void gload_lds16(const void* g, void* l) {
    auto gp = (const __attribute__((address_space(1))) void*)(uintptr_t)g;
    auto lp = (__attribute__((address_space(3))) void*)(uintptr_t)l;
    __builtin_amdgcn_global_load_lds(gp, lp, 16, 0, 0);
}

// lane n <- lane n-1 across the whole wave; lane 0 keeps old (overridden).
__device__ __forceinline__ int shl1w_i(int s) {
    return __builtin_amdgcn_update_dpp(s, s, 0x138 /*wave_shr:1*/, 0xF, 0xF, false);
}
__device__ __forceinline__ float shl1w_f(float s) {
    return __int_as_float(shl1w_i(__float_as_int(s)));
}

// 8x ds_read_b128: 128B burst into pinned registers (opaque to remat).
__device__ __forceinline__ void burst8(unsigned addr, u32x4 (&d)[8]) {
    asm volatile(
        "ds_read_b128 %0, %8 offset:0\n\t"
        "ds_read_b128 %1, %8 offset:16\n\t"
        "ds_read_b128 %2, %8 offset:32\n\t"
        "ds_read_b128 %3, %8 offset:48\n\t"
        "ds_read_b128 %4, %8 offset:64\n\t"
        "ds_read_b128 %5, %8 offset:80\n\t"
        "ds_read_b128 %6, %8 offset:96\n\t"
        "ds_read_b128 %7, %8 offset:112"
        : "=&v"(d[0]), "=&v"(d[1]), "=&v"(d[2]), "=&v"(d[3]),
          "=&v"(d[4]), "=&v"(d[5]), "=&v"(d[6]), "=&v"(d[7])
        : "v"(addr));
}

// acc += s * f16(lo/hi of p)   -- one v_fma_mix_f32, f16 source in S1
#define FMA_MIX_LO(acc, s, p)                                              \
    asm("v_fma_mix_f32 %0, %1, %2, %0 op_sel:[0,0,0] op_sel_hi:[0,1,0]"    \
        : "+v"(acc) : "v"(s), "v"(p))
#define FMA_MIX_HI(acc, s, p)                                              \
    asm("v_fma_mix_f32 %0, %1, %2, %0 op_sel:[0,1,0] op_sel_hi:[0,1,0]"    \
        : "+v"(acc) : "v"(s), "v"(p))

__global__ __launch_bounds__(64, 1)
void ctc_scan(const u32x4* __restrict__ xq, const int* __restrict__ seqs,
              const int* __restrict__ seqlens, float* __restrict__ out) {
    __shared__ __align__(16) u32x4 ring[512];      // 8 KB: 8 chunks x 64 rows
    __shared__ float garr[PP + 1];

    const int b = blockIdx.x;
    const int l = threadIdx.x;                     // 0..63
    const bool lane0 = (l == 0);

    // per-lane v_perm byte controls (value i at bytes 2i,2i+1 of {row[1]:row[0]})
    unsigned ctrl[4];
#pragma unroll
    for (int k = 0; k < 4; ++k) {
        unsigned i0 = (unsigned)seqs[b * PP + 8 * l + 2 * k];
        unsigned i1 = (unsigned)seqs[b * PP + 8 * l + 2 * k + 1];
        ctrl[k] = (2 * i0) | ((2 * i0 + 1) << 8) | ((2 * i1) << 16) | ((2 * i1 + 1) << 24);
    }

    // column-major: row t of batch b at xq[b*4096 + t]; fully coalesced staging.
    const u32x4* gsrc = xq + (size_t)b * 4096;

    // ---- stage chunks 0..3 (64 rows each) ----
#pragma unroll
    for (int c0 = 0; c0 < 4; ++c0)
        gload_lds16(gsrc + c0 * 64 + l, &ring[c0 * 64 + l]);
    asm volatile("s_waitcnt vmcnt(3)" ::: "memory");   // chunk 0 resident

    const unsigned ring_base =
        (unsigned)(uintptr_t)(__attribute__((address_space(3))) void*)&ring[0];

    // ---- prologue: burst windows 0,1 into X,Y ----
    u32x4 wX[8], wY[8], wZ[8];
    burst8(ring_base, wX);
    burst8(ring_base + 128, wY);
    int nrow = 16;                                 // ring row of next burst

    float F[8];                                    // G values, frame 2^M
#pragma unroll
    for (int i = 0; i < 8; ++i) F[i] = 0.0f;
    int M = 0;
    float logs = 0.0f;                             // sum of x_4

    auto window = [&](int i, u32x4 (&cur)[8], u32x4 (&nxt)[8]) {
        if ((i & 7) == 0) {                        // chunk staging, every 8 windows
            int c = i >> 3;
            if (c < 64) {
                int cs = (c + 4 > 63) ? 63 : (c + 4);
                gload_lds16(gsrc + cs * 64 + l, &ring[((c + 4) & 7) * 64 + l]);
                asm volatile("s_waitcnt vmcnt(3)" ::: "memory");  // chunk c+1 resident
            }
        }
        // cur's burst was issued 2 windows ago; the 1-ahead burst (8 reads)
        // may stay in flight: wait until <=8 outstanding.
        asm volatile("s_waitcnt lgkmcnt(8)" ::: "memory");
        __builtin_amdgcn_sched_barrier(0);
        burst8(ring_base + (unsigned)((nrow & 511) * 16), nxt);
        nrow += 8;
        __builtin_amdgcn_sched_barrier(0);

        if (i < 512) {
            // ---- window bookkeeping: renorm + neighbor frame alignment ----
            float m = F[0];
#pragma unroll
            for (int k = 1; k < 8; ++k) m = fmaxf(m, F[k]);
            int e2 = ((__float_as_int(m) >> 23) & 0xFF) - 127;
            e2 = (m > 0.0f) ? e2 : 0;
            const int Mp = M + e2;                 // post-renorm frame
            const int Mlp = shl1w_i(Mp);           // neighbor's post-renorm frame
            int dl = (lane0 ? 0 : Mlp) - Mp;       // lane0 left neighbor: G[0]=1, frame 0
            int dlc = dl > 0 ? dl : 0;             // down-only self-squash
            const int Mnew = Mp + dlc;
            const int sh = Mnew - M;               // >= 0
#pragma unroll
            for (int k = 0; k < 8; ++k) F[k] = ldexpf(F[k], -sh);
            M = Mnew;
            int dn = Mlp - M; dn = dn > 0 ? 0 : dn;
            const float sA   = ldexpf(1.0f, dn);   // neighbor -> my frame
            const float sAx  = lane0 ? 0.0f : sA;
            const float cfin = lane0 ? ldexpf(1.0f, -M) : 0.0f;  // G[0]=1 in my frame

            // ---- 8 steps: F[k] += Fs[k] * W[k] (forced v_fma_mix_f32) ----
#pragma unroll
            for (int u = 0; u < 8; ++u) {
                const u32x4 row = cur[u];
                logs += __uint_as_float(row[2]);
                unsigned p0 = __builtin_amdgcn_perm(row[1], row[0], ctrl[0]);
                unsigned p1 = __builtin_amdgcn_perm(row[1], row[0], ctrl[1]);
                unsigned p2 = __builtin_amdgcn_perm(row[1], row[0], ctrl[2]);
                unsigned p3 = __builtin_amdgcn_perm(row[1], row[0], ctrl[3]);

                const float Flr = shl1w_f(F[7]);   // 1 DPP: lane n <- n-1
                const float fin = fmaf(Flr, sAx, cfin);

                FMA_MIX_HI(F[7], F[6], p3);
                FMA_MIX_LO(F[6], F[5], p3);
                FMA_MIX_HI(F[5], F[4], p2);
                FMA_MIX_LO(F[4], F[3], p2);
                FMA_MIX_HI(F[3], F[2], p1);
                FMA_MIX_LO(F[2], F[1], p1);
                FMA_MIX_HI(F[1], F[0], p0);
                FMA_MIX_LO(F[0], fin,  p0);
            }
        }
    };

    // 513 windows (513 = 3*171): 512 active + 1 guard; 3-way rotation keeps
    // the 2-ahead burst pattern static.
#pragma unroll 1
    for (int i = 0; i < 513; i += 3) {
        window(i,     wX, wZ);
        window(i + 1, wY, wX);
        window(i + 2, wZ, wY);
    }
    // drain in-flight bursts, then pin their dest regs until after the drain
    asm volatile("s_waitcnt lgkmcnt(0)" ::: "memory");
    __builtin_amdgcn_sched_barrier(0);
    asm volatile("" ::
        "v"(wX[0]), "v"(wX[1]), "v"(wX[2]), "v"(wX[3]),
        "v"(wX[4]), "v"(wX[5]), "v"(wX[6]), "v"(wX[7]),
        "v"(wY[0]), "v"(wY[1]), "v"(wY[2]), "v"(wY[3]),
        "v"(wY[4]), "v"(wY[5]), "v"(wY[6]), "v"(wY[7]),
        "v"(wZ[0]), "v"(wZ[1]), "v"(wZ[2]), "v"(wZ[3]),
        "v"(wZ[4]), "v"(wZ[5]), "v"(wZ[6]), "v"(wZ[7]));

    // ---- epilogue: log2 reconstruction (denormal-safe) ----
    const float lgS = logs * 1.44269504088896341f;  // log2(prod S)
#pragma unroll
    for (int i = 0; i < 8; ++i) {
        float v = fmaxf(F[i] * 16777216.0f, 1e-38f);
        garr[8 * l + 1 + i] = __log2f(v) - 24.0f + (float)M + lgS;
    }
    if (lane0) garr[0] = lgS;                       // position 0: log2(1) + lgS
    __syncthreads();
    if (lane0) {
        const int sl = seqlens[b];
        out[b] = -(garr[sl] * LN2F) / (float)TT;
    }
}

extern "C" void kernel_launch(void* const* d_in, const int* in_sizes, int n_in,
                              void* d_out, int out_size, void* d_ws, size_t ws_size,
                              hipStream_t stream) {
    const float* x       = (const float*)d_in[0];
    const int*   seqs    = (const int*)d_in[1];
    const int*   seqlens = (const int*)d_in[2];
    float*       out     = (float*)d_out;
    u32x4*       xq      = (u32x4*)d_ws;           // TT*BB rows x 16 B = 4 MB

    ctc_prepass<<<(TT * BB) / 256, 256, 0, stream>>>(x, xq);
    ctc_scan<<<BB, 64, 0, stream>>>(xq, seqs, seqlens, out);
}